// Round 7
// baseline (316.916 us; speedup 1.0000x reference)
//
#include <hip/hip_runtime.h>
#include <math.h>

#define NH 32
#define NKVH 8
#define GRP 4
#define HD 128
#define LQB 128
#define B_SEQ 8
#define PTSTRIDE 128
#define KVROW (NKVH * HD)          // 1024 floats per token row
#define QK_SCALE 0.08838834764831845f
#define LOG2E 1.4426950408889634f
#define DEFER_THR 8.0f
#define NROWS (B_SEQ * LQB * NH)   // 32768 (q-row, head) pairs

typedef __attribute__((ext_vector_type(8)))  __bf16 bf16x8;
typedef __attribute__((ext_vector_type(4)))  __bf16 bf16x4;
typedef __attribute__((ext_vector_type(4)))  float  f32x4;
typedef __attribute__((ext_vector_type(16))) float  f32x16;

// LDS per buffer: K: 32 keys x 128 d bf16, 256B rows, 16-slot XOR swizzle ((key&15)<<4)
//                 Vt: 128 d x 40 keys bf16 (80B rows; PV b128 reads land 8/bank = free)
#define KS_BYTES 8192
#define VT_STRIDE 80
#define VT_BYTES 10240
#define KS_OFF(bu) ((bu) * KS_BYTES)
#define VT_OFF(bu) (2 * KS_BYTES + (bu) * VT_BYTES)
// total LDS = 36864 B -> 3 blocks/CU (VGPR-capped), 110 KB of 160 KB

static __device__ __forceinline__ bf16x8 cvt8s(const float* __restrict__ p, float s) {
    const f32x4 a = *reinterpret_cast<const f32x4*>(p);
    const f32x4 b = *reinterpret_cast<const f32x4*>(p + 4);
    bf16x8 r;
    r[0] = (__bf16)(a[0] * s); r[1] = (__bf16)(a[1] * s);
    r[2] = (__bf16)(a[2] * s); r[3] = (__bf16)(a[3] * s);
    r[4] = (__bf16)(b[0] * s); r[5] = (__bf16)(b[1] * s);
    r[6] = (__bf16)(b[2] * s); r[7] = (__bf16)(b[3] * s);
    return r;
}

// Wave = 32 q-rows of one head (32x32x16 MFMAs); block = 4 heads of one kv group
// sharing K/V in LDS. S^T = K*Q^T: C col = lane&31 = q -> softmax per-q exact,
// 1 shfl_xor(32) for the max. PV = P*V with a half-lane key exchange for the
// P A-fragment (A and B share the same k-slot map -> permutation-invariant).
// Kernel stores UNNORMALIZED O + (m,l); combine<> normalizes / merges splits.
template<int NSPLIT>
__global__ __launch_bounds__(256, 3)
void attn_fwd(const float* __restrict__ Q,
              const float* __restrict__ Kn,
              const float* __restrict__ Vn,
              const float* __restrict__ Kc,
              const float* __restrict__ Vc,
              const int* __restrict__ PT,
              const int* __restrict__ CTX,
              float* __restrict__ WA,      // [NSPLIT][NROWS][HD] unnormalized partial O
              float2* __restrict__ WML)    // [NSPLIT][NROWS] (m, l), log2 domain
{
    __shared__ __align__(16) unsigned char smem[2 * KS_BYTES + 2 * VT_BYTES];

    const int ctx  = CTX[0];                 // 2048 (multiple of 32)
    const int tid  = (int)threadIdx.x;
    const int wave = tid >> 6;
    const int lane = tid & 63;
    const int c31  = lane & 31;              // q column (S^T/C) and d column (PV/C)
    const int hl   = lane >> 5;

    const int bid   = (int)blockIdx.x;       // kvh in low bits -> XCD affinity
    const int kvh   = bid & 7;
    const int b     = (bid >> 3) & 7;
    const int qtile = (bid >> 6) & 3;        // 32-row q tiles (uniform visibility)
    const int sk    = (NSPLIT > 1) ? (bid >> 8) : 0;
    const int head  = kvh * GRP + wave;
    const int q0    = qtile * 32;

    // Q fragments: qf[c][j] = Q[q0+c31][16c + 8hl + j] * scale*log2e
    const float* qrow = Q + (size_t)(b * LQB + q0 + c31) * (NH * HD) + head * HD;
    bf16x8 qf[8];
    #pragma unroll
    for (int c = 0; c < 8; ++c) qf[c] = cvt8s(qrow + 16 * c + 8 * hl, QK_SCALE * LOG2E);

    f32x16 acc[4];                           // O[q][32g + c31], q = (r&3)+8(r>>2)+4hl
    #pragma unroll
    for (int g = 0; g < 4; ++g)
        #pragma unroll
        for (int r = 0; r < 16; ++r) acc[g][r] = 0.f;
    float mrun = -1e30f, lsum = 0.f;         // per-q (q = c31) running max / denom

    const int vis  = ctx + q0 + 32;          // visible keys (multiple of 32)
    const int nt   = vis >> 5;
    const int kbeg = ((nt * sk) / NSPLIT) << 5;
    const int kend = ((nt * (sk + 1)) / NSPLIT) << 5;
    const int nsteps = (kend - kbeg) >> 5;

    // staging ids (unchanged from the 146us anchor)
    const int skey = tid >> 3;               // K: key row 0..31
    const int sc8  = tid & 7;                // K: 16-float col chunk
    const int kxr  = (skey & 15) << 4;       // 16-slot swizzle
    const int vdc  = tid >> 3;               // V: d-chunk (4 floats) 0..31
    const int vkq  = tid & 7;                // V: key quad 0..7

    f32x4 kr[4], vr[4];

    auto issue_loads = [&](int t0) {
        {
            const int tok = t0 + skey;
            const float* src; size_t ro;
            if (tok < ctx) {
                const int pg = PT[b * PTSTRIDE + (tok >> 4)];
                src = Kc; ro = ((size_t)pg * 16 + (tok & 15)) * KVROW + kvh * HD;
            } else {
                src = Kn; ro = (size_t)(b * LQB + tok - ctx) * KVROW + kvh * HD;
            }
            const f32x4* p = reinterpret_cast<const f32x4*>(src + ro + 16 * sc8);
            kr[0] = p[0]; kr[1] = p[1]; kr[2] = p[2]; kr[3] = p[3];
        }
        {
            const int tok0 = t0 + 4 * vkq;
            const float* src; size_t ro;
            if (tok0 < ctx) {
                const int pg = PT[b * PTSTRIDE + (tok0 >> 4)];
                src = Vc; ro = ((size_t)pg * 16 + (tok0 & 15)) * KVROW + kvh * HD;
            } else {
                src = Vn; ro = (size_t)(b * LQB + tok0 - ctx) * KVROW + kvh * HD;
            }
            const float* base = src + ro + 4 * vdc;
            vr[0] = *reinterpret_cast<const f32x4*>(base);
            vr[1] = *reinterpret_cast<const f32x4*>(base + KVROW);
            vr[2] = *reinterpret_cast<const f32x4*>(base + 2 * KVROW);
            vr[3] = *reinterpret_cast<const f32x4*>(base + 3 * KVROW);
        }
    };

    auto write_tile = [&](int bu) {
        unsigned char* ks = smem + KS_OFF(bu) + skey * 256;
        bf16x8 c0w, c1w;
        #pragma unroll
        for (int j = 0; j < 4; ++j) {
            c0w[j] = (__bf16)kr[0][j]; c0w[j + 4] = (__bf16)kr[1][j];
            c1w[j] = (__bf16)kr[2][j]; c1w[j + 4] = (__bf16)kr[3][j];
        }
        *reinterpret_cast<bf16x8*>(ks + ((32 * sc8) ^ kxr))      = c0w;
        *reinterpret_cast<bf16x8*>(ks + ((32 * sc8 + 16) ^ kxr)) = c1w;
        unsigned char* vt = smem + VT_OFF(bu) + 8 * vkq;
        #pragma unroll
        for (int di = 0; di < 4; ++di) {
            bf16x4 w;
            w[0] = (__bf16)vr[0][di]; w[1] = (__bf16)vr[1][di];
            w[2] = (__bf16)vr[2][di]; w[3] = (__bf16)vr[3][di];
            *reinterpret_cast<bf16x4*>(vt + (4 * vdc + di) * VT_STRIDE) = w;
        }
    };

    auto tile_barrier = [&]() {
        asm volatile("s_waitcnt lgkmcnt(0)" ::: "memory");
        __builtin_amdgcn_s_barrier();
    };

    issue_loads(kbeg);
    write_tile(0);
    if (nsteps > 1) issue_loads(kbeg + 32);
    tile_barrier();

    int cur = 0;
    for (int s = 0; s < nsteps; ++s) {
        if (s + 1 < nsteps) write_tile(cur ^ 1);
        if (s + 2 < nsteps) issue_loads(kbeg + ((s + 2) << 5));

        const unsigned char* ks = smem + KS_OFF(cur);
        const unsigned char* vt = smem + VT_OFF(cur);
        const int xr = (c31 & 15) << 4;

        // S^T[key=c31][q]: 8 chained 32x32x16 MFMAs over d
        f32x16 sc;
        #pragma unroll
        for (int r = 0; r < 16; ++r) sc[r] = 0.f;
        #pragma unroll
        for (int c = 0; c < 8; ++c) {
            bf16x8 kf = *reinterpret_cast<const bf16x8*>(
                ks + c31 * 256 + ((((2 * c + hl) << 4)) ^ xr));
            sc = __builtin_amdgcn_mfma_f32_32x32x16_bf16(kf, qf[c], sc, 0, 0, 0);
        }

        // per-q max over the lane's 16 keys + partner half
        float pm = sc[0];
        #pragma unroll
        for (int r = 1; r < 16; ++r) pm = fmaxf(pm, sc[r]);
        pm = fmaxf(pm, __shfl_xor(pm, 32));

        // deferred-max rescale (rare): corr is per-q -> broadcast via shfl
        if (!__all(pm - mrun <= DEFER_THR)) {
            const float mnew = fmaxf(mrun, pm);
            const float corr = exp2f(mrun - mnew);
            mrun = mnew;
            lsum *= corr;
            #pragma unroll
            for (int r = 0; r < 16; ++r) {
                const int qr = (r & 3) + 8 * (r >> 2) + 4 * hl;
                const float cr = __shfl(corr, qr);
                #pragma unroll
                for (int g = 0; g < 4; ++g) acc[g][r] *= cr;
            }
        }

        float p[16];
        float ss = 0.f;
        #pragma unroll
        for (int r = 0; r < 16; ++r) {
            p[r] = exp2f(sc[r] - mrun);      // sc is for q = c31 -> own mrun
            ss += p[r];
        }
        lsum += ss;                          // own half only; partner added at end

        // PV: A = P (row=q=c31, slot j <-> key 16h+8hl+j), B = V same k-map
        #pragma unroll
        for (int h = 0; h < 2; ++h) {
            union { bf16x4 h4; uint2 u2; } U, W;
            #pragma unroll
            for (int m = 0; m < 4; ++m) {
                U.h4[m] = (__bf16)p[8 * h + m];
                W.h4[m] = (__bf16)p[8 * h + 4 + m];
            }
            const unsigned sux = __shfl_xor(U.u2.x, 32), suy = __shfl_xor(U.u2.y, 32);
            const unsigned swx = __shfl_xor(W.u2.x, 32), swy = __shfl_xor(W.u2.y, 32);
            union { bf16x8 h8; unsigned u[4]; } PF;
            PF.u[0] = hl ? swx : U.u2.x;     // slots 0-3
            PF.u[1] = hl ? swy : U.u2.y;
            PF.u[2] = hl ? W.u2.x : sux;     // slots 4-7
            PF.u[3] = hl ? W.u2.y : suy;
            #pragma unroll
            for (int g = 0; g < 4; ++g) {
                bf16x8 vf = *reinterpret_cast<const bf16x8*>(
                    vt + (32 * g + c31) * VT_STRIDE + 32 * h + 16 * hl);
                acc[g] = __builtin_amdgcn_mfma_f32_32x32x16_bf16(PF.h8, vf, acc[g], 0, 0, 0);
            }
        }

        if (s + 1 < nsteps) tile_barrier();
        cur ^= 1;
    }

    lsum += __shfl_xor(lsum, 32);

    // unnormalized store; combine<> divides by l (and merges splits)
    #pragma unroll
    for (int g = 0; g < 4; ++g)
        #pragma unroll
        for (int r = 0; r < 16; ++r) {
            const int qr = (r & 3) + 8 * (r >> 2) + 4 * hl;
            WA[((size_t)sk * NROWS + (size_t)(b * LQB + q0 + qr) * NH + head) * HD
               + 32 * g + c31] = acc[g][r];
        }
    if (lane < 32)
        WML[sk * NROWS + (b * LQB + q0 + lane) * NH + head] = make_float2(mrun, lsum);
}

template<int NSPLIT>
__global__ __launch_bounds__(256)
void combine(const float* __restrict__ WA, const float2* __restrict__ WML,
             float* __restrict__ O)
{
    const int idx = (int)blockIdx.x * 256 + (int)threadIdx.x;  // NROWS*32 threads
    const int r  = idx >> 5;
    const int dq = idx & 31;
    float2 ml[NSPLIT];
    float M = -1e30f;
    #pragma unroll
    for (int s = 0; s < NSPLIT; ++s) { ml[s] = WML[s * NROWS + r]; M = fmaxf(M, ml[s].x); }
    float e[NSPLIT];
    float den = 0.f;
    #pragma unroll
    for (int s = 0; s < NSPLIT; ++s) { e[s] = exp2f(ml[s].x - M); den += ml[s].y * e[s]; }
    const float inv = 1.0f / den;
    f32x4 o = (f32x4){0.f, 0.f, 0.f, 0.f};
    #pragma unroll
    for (int s = 0; s < NSPLIT; ++s) {
        const f32x4 a = *reinterpret_cast<const f32x4*>(WA + ((size_t)s * NROWS + r) * HD + 4 * dq);
        o += a * e[s];
    }
    o *= inv;
    *reinterpret_cast<f32x4*>(O + (size_t)r * HD + 4 * dq) = o;
}

extern "C" void kernel_launch(void* const* d_in, const int* in_sizes, int n_in,
                              void* d_out, int out_size, void* d_ws, size_t ws_size,
                              hipStream_t stream) {
    const float* q  = (const float*)d_in[0];
    const float* k  = (const float*)d_in[1];
    const float* v  = (const float*)d_in[2];
    const float* kc = (const float*)d_in[3];
    const float* vc = (const float*)d_in[4];
    const int*   pt = (const int*)d_in[5];
    const int*   cx = (const int*)d_in[6];
    float* out = (float*)d_out;

    const size_t waN = (size_t)NROWS * HD * sizeof(float);
    const size_t mlN = (size_t)NROWS * sizeof(float2);

    if (ws_size >= 3 * (waN + mlN)) {
        float*  wa  = (float*)d_ws;
        float2* wml = (float2*)((char*)d_ws + 3 * waN);
        attn_fwd<3><<<dim3(768), dim3(256), 0, stream>>>(q, k, v, kc, vc, pt, cx, wa, wml);
        combine<3><<<dim3(NROWS * 32 / 256), dim3(256), 0, stream>>>(wa, wml, out);
    } else if (ws_size >= 2 * (waN + mlN)) {
        float*  wa  = (float*)d_ws;
        float2* wml = (float2*)((char*)d_ws + 2 * waN);
        attn_fwd<2><<<dim3(512), dim3(256), 0, stream>>>(q, k, v, kc, vc, pt, cx, wa, wml);
        combine<2><<<dim3(NROWS * 32 / 256), dim3(256), 0, stream>>>(wa, wml, out);
    } else {
        float*  wa  = (float*)d_ws;
        float2* wml = (float2*)((char*)d_ws + waN);
        attn_fwd<1><<<dim3(256), dim3(256), 0, stream>>>(q, k, v, kc, vc, pt, cx, wa, wml);
        combine<1><<<dim3(NROWS * 32 / 256), dim3(256), 0, stream>>>(wa, wml, out);
    }
}

// Round 8
// 244.584 us; speedup vs baseline: 1.2957x; 1.2957x over previous
//
#include <hip/hip_runtime.h>
#include <math.h>

#define NH 32
#define NKVH 8
#define GRP 4
#define HD 128
#define LQB 128
#define B_SEQ 8
#define PTSTRIDE 128
#define KVROW (NKVH * HD)          // 1024 floats per token row
#define QK_SCALE 0.08838834764831845f
#define LOG2E 1.4426950408889634f
#define DEFER_THR 8.0f
#define NROWS (B_SEQ * LQB * NH)   // 32768 (q-row, head) pairs

typedef __attribute__((ext_vector_type(8)))  __bf16 bf16x8;
typedef __attribute__((ext_vector_type(4)))  __bf16 bf16x4;
typedef __attribute__((ext_vector_type(4)))  float  f32x4;
typedef __attribute__((ext_vector_type(16))) float  f32x16;

// LDS per buffer: K: 32 keys x 128 d bf16, 256B rows, 16-slot XOR swizzle ((key&15)<<4)
//                 Vt: 128 d x 40 keys bf16 (80B rows; PV b128 reads conflict-light)
#define KS_BYTES 8192
#define VT_STRIDE 80
#define VT_BYTES 10240
#define KS_OFF(bu) ((bu) * KS_BYTES)
#define VT_OFF(bu) (2 * KS_BYTES + (bu) * VT_BYTES)
// total LDS = 36864 B; 2 blocks/CU (VGPR-roomy, no spill)

static __device__ __forceinline__ bf16x8 cvt8s(const float* __restrict__ p, float s) {
    const f32x4 a = *reinterpret_cast<const f32x4*>(p);
    const f32x4 b = *reinterpret_cast<const f32x4*>(p + 4);
    bf16x8 r;
    r[0] = (__bf16)(a[0] * s); r[1] = (__bf16)(a[1] * s);
    r[2] = (__bf16)(a[2] * s); r[3] = (__bf16)(a[3] * s);
    r[4] = (__bf16)(b[0] * s); r[5] = (__bf16)(b[1] * s);
    r[6] = (__bf16)(b[2] * s); r[7] = (__bf16)(b[3] * s);
    return r;
}

// Wave = 32 q-rows of one head (32x32x16 MFMAs); block = 4 heads of one kv group
// sharing K/V in LDS. S^T = K*Q^T split into TWO independent d-half chains
// (sc0: d<64, sc1: d>=64) summed before softmax. C col = lane&31 = q -> softmax
// per-q exact, 1 shfl_xor(32). PV = P*V with half-lane key exchange for the P
// A-fragment (A/B share the same k-slot map -> permutation-invariant).
// Stores UNNORMALIZED O + (m,l); combine<> normalizes / merges splits.
// launch_bounds(256,2): cap 256 VGPR -- the (256,3) build spilled (VGPR=84 sentinel).
template<int NSPLIT>
__global__ __launch_bounds__(256, 2)
void attn_fwd(const float* __restrict__ Q,
              const float* __restrict__ Kn,
              const float* __restrict__ Vn,
              const float* __restrict__ Kc,
              const float* __restrict__ Vc,
              const int* __restrict__ PT,
              const int* __restrict__ CTX,
              float* __restrict__ WA,      // [NSPLIT][NROWS][HD] unnormalized partial O
              float2* __restrict__ WML)    // [NSPLIT][NROWS] (m, l), log2 domain
{
    __shared__ __align__(16) unsigned char smem[2 * KS_BYTES + 2 * VT_BYTES];

    const int ctx  = CTX[0];                 // 2048 (multiple of 32)
    const int tid  = (int)threadIdx.x;
    const int wave = tid >> 6;
    const int lane = tid & 63;
    const int c31  = lane & 31;              // q column (S^T/C) and d column (PV/C)
    const int hl   = lane >> 5;

    const int bid   = (int)blockIdx.x;       // kvh in low bits -> XCD affinity
    const int kvh   = bid & 7;
    const int b     = (bid >> 3) & 7;
    const int qtile = (bid >> 6) & 3;        // 32-row q tiles (uniform visibility)
    const int sk    = (NSPLIT > 1) ? (bid >> 8) : 0;
    const int head  = kvh * GRP + wave;
    const int q0    = qtile * 32;

    // Q fragments: qf[c][j] = Q[q0+c31][16c + 8hl + j] * scale*log2e
    const float* qrow = Q + (size_t)(b * LQB + q0 + c31) * (NH * HD) + head * HD;
    bf16x8 qf[8];
    #pragma unroll
    for (int c = 0; c < 8; ++c) qf[c] = cvt8s(qrow + 16 * c + 8 * hl, QK_SCALE * LOG2E);

    f32x16 acc[4];                           // O[q][32g + c31], q = (r&3)+8(r>>2)+4hl
    #pragma unroll
    for (int g = 0; g < 4; ++g)
        #pragma unroll
        for (int r = 0; r < 16; ++r) acc[g][r] = 0.f;
    float mrun = -1e30f, lsum = 0.f;         // per-q (q = c31) running max / denom

    const int vis  = ctx + q0 + 32;          // visible keys (multiple of 32)
    const int nt   = vis >> 5;
    const int kbeg = ((nt * sk) / NSPLIT) << 5;
    const int kend = ((nt * (sk + 1)) / NSPLIT) << 5;
    const int nsteps = (kend - kbeg) >> 5;

    // staging ids
    const int skey = tid >> 3;               // K: key row 0..31
    const int sc8  = tid & 7;                // K: 16-float col chunk
    const int kxr  = (skey & 15) << 4;       // 16-slot swizzle
    const int vdc  = tid >> 3;               // V: d-chunk (4 floats) 0..31
    const int vkq  = tid & 7;                // V: key quad 0..7

    f32x4 kr[4], vr[4];

    auto issue_loads = [&](int t0) {
        {
            const int tok = t0 + skey;
            const float* src; size_t ro;
            if (tok < ctx) {
                const int pg = PT[b * PTSTRIDE + (tok >> 4)];
                src = Kc; ro = ((size_t)pg * 16 + (tok & 15)) * KVROW + kvh * HD;
            } else {
                src = Kn; ro = (size_t)(b * LQB + tok - ctx) * KVROW + kvh * HD;
            }
            const f32x4* p = reinterpret_cast<const f32x4*>(src + ro + 16 * sc8);
            kr[0] = p[0]; kr[1] = p[1]; kr[2] = p[2]; kr[3] = p[3];
        }
        {
            const int tok0 = t0 + 4 * vkq;
            const float* src; size_t ro;
            if (tok0 < ctx) {
                const int pg = PT[b * PTSTRIDE + (tok0 >> 4)];
                src = Vc; ro = ((size_t)pg * 16 + (tok0 & 15)) * KVROW + kvh * HD;
            } else {
                src = Vn; ro = (size_t)(b * LQB + tok0 - ctx) * KVROW + kvh * HD;
            }
            const float* base = src + ro + 4 * vdc;
            vr[0] = *reinterpret_cast<const f32x4*>(base);
            vr[1] = *reinterpret_cast<const f32x4*>(base + KVROW);
            vr[2] = *reinterpret_cast<const f32x4*>(base + 2 * KVROW);
            vr[3] = *reinterpret_cast<const f32x4*>(base + 3 * KVROW);
        }
    };

    auto write_tile = [&](int bu) {
        unsigned char* ks = smem + KS_OFF(bu) + skey * 256;
        bf16x8 c0w, c1w;
        #pragma unroll
        for (int j = 0; j < 4; ++j) {
            c0w[j] = (__bf16)kr[0][j]; c0w[j + 4] = (__bf16)kr[1][j];
            c1w[j] = (__bf16)kr[2][j]; c1w[j + 4] = (__bf16)kr[3][j];
        }
        *reinterpret_cast<bf16x8*>(ks + ((32 * sc8) ^ kxr))      = c0w;
        *reinterpret_cast<bf16x8*>(ks + ((32 * sc8 + 16) ^ kxr)) = c1w;
        unsigned char* vt = smem + VT_OFF(bu) + 8 * vkq;
        #pragma unroll
        for (int di = 0; di < 4; ++di) {
            bf16x4 w;
            w[0] = (__bf16)vr[0][di]; w[1] = (__bf16)vr[1][di];
            w[2] = (__bf16)vr[2][di]; w[3] = (__bf16)vr[3][di];
            *reinterpret_cast<bf16x4*>(vt + (4 * vdc + di) * VT_STRIDE) = w;
        }
    };

    auto tile_barrier = [&]() {
        asm volatile("s_waitcnt lgkmcnt(0)" ::: "memory");
        __builtin_amdgcn_s_barrier();
    };

    issue_loads(kbeg);
    write_tile(0);
    if (nsteps > 1) issue_loads(kbeg + 32);
    tile_barrier();

    int cur = 0;
    for (int s = 0; s < nsteps; ++s) {
        if (s + 1 < nsteps) write_tile(cur ^ 1);
        if (s + 2 < nsteps) issue_loads(kbeg + ((s + 2) << 5));

        const unsigned char* ks = smem + KS_OFF(cur);
        const unsigned char* vt = smem + VT_OFF(cur);
        const int xr = (c31 & 15) << 4;

        // S^T[key=c31][q]: two independent 4-deep MFMA chains over d-halves
        f32x16 sc0, sc1;
        #pragma unroll
        for (int r = 0; r < 16; ++r) { sc0[r] = 0.f; sc1[r] = 0.f; }
        #pragma unroll
        for (int c = 0; c < 4; ++c) {
            bf16x8 kf0 = *reinterpret_cast<const bf16x8*>(
                ks + c31 * 256 + (((2 * c + hl) << 4) ^ xr));
            bf16x8 kf1 = *reinterpret_cast<const bf16x8*>(
                ks + c31 * 256 + (((2 * (c + 4) + hl) << 4) ^ xr));
            sc0 = __builtin_amdgcn_mfma_f32_32x32x16_bf16(kf0, qf[c], sc0, 0, 0, 0);
            sc1 = __builtin_amdgcn_mfma_f32_32x32x16_bf16(kf1, qf[c + 4], sc1, 0, 0, 0);
        }
        #pragma unroll
        for (int r = 0; r < 16; ++r) sc0[r] += sc1[r];

        // per-q max over the lane's 16 keys + partner half
        float pm = sc0[0];
        #pragma unroll
        for (int r = 1; r < 16; ++r) pm = fmaxf(pm, sc0[r]);
        pm = fmaxf(pm, __shfl_xor(pm, 32));

        // deferred-max rescale (rare): corr is per-q -> broadcast via shfl
        if (!__all(pm - mrun <= DEFER_THR)) {
            const float mnew = fmaxf(mrun, pm);
            const float corr = exp2f(mrun - mnew);
            mrun = mnew;
            lsum *= corr;
            #pragma unroll
            for (int r = 0; r < 16; ++r) {
                const int qr = (r & 3) + 8 * (r >> 2) + 4 * hl;
                const float cr = __shfl(corr, qr);
                #pragma unroll
                for (int g = 0; g < 4; ++g) acc[g][r] *= cr;
            }
        }

        float p[16];
        float ss = 0.f;
        #pragma unroll
        for (int r = 0; r < 16; ++r) {
            p[r] = exp2f(sc0[r] - mrun);     // sc0 is for q = c31 -> own mrun
            ss += p[r];
        }
        lsum += ss;                          // own half only; partner added at end

        // PV: A = P (row=q=c31, slot j <-> key 16h+8hl+j), B = V same k-map
        #pragma unroll
        for (int h = 0; h < 2; ++h) {
            union { bf16x4 h4; uint2 u2; } U, W;
            #pragma unroll
            for (int m = 0; m < 4; ++m) {
                U.h4[m] = (__bf16)p[8 * h + m];
                W.h4[m] = (__bf16)p[8 * h + 4 + m];
            }
            const unsigned sux = __shfl_xor(U.u2.x, 32), suy = __shfl_xor(U.u2.y, 32);
            const unsigned swx = __shfl_xor(W.u2.x, 32), swy = __shfl_xor(W.u2.y, 32);
            union { bf16x8 h8; unsigned u[4]; } PF;
            PF.u[0] = hl ? swx : U.u2.x;     // slots 0-3
            PF.u[1] = hl ? swy : U.u2.y;
            PF.u[2] = hl ? W.u2.x : sux;     // slots 4-7
            PF.u[3] = hl ? W.u2.y : suy;
            #pragma unroll
            for (int g = 0; g < 4; ++g) {
                bf16x8 vf = *reinterpret_cast<const bf16x8*>(
                    vt + (32 * g + c31) * VT_STRIDE + 32 * h + 16 * hl);
                acc[g] = __builtin_amdgcn_mfma_f32_32x32x16_bf16(PF.h8, vf, acc[g], 0, 0, 0);
            }
        }

        if (s + 1 < nsteps) tile_barrier();
        cur ^= 1;
    }

    lsum += __shfl_xor(lsum, 32);

    // unnormalized store; combine<> divides by l (and merges splits)
    #pragma unroll
    for (int g = 0; g < 4; ++g)
        #pragma unroll
        for (int r = 0; r < 16; ++r) {
            const int qr = (r & 3) + 8 * (r >> 2) + 4 * hl;
            WA[((size_t)sk * NROWS + (size_t)(b * LQB + q0 + qr) * NH + head) * HD
               + 32 * g + c31] = acc[g][r];
        }
    if (lane < 32)
        WML[sk * NROWS + (b * LQB + q0 + lane) * NH + head] = make_float2(mrun, lsum);
}

template<int NSPLIT>
__global__ __launch_bounds__(256)
void combine(const float* __restrict__ WA, const float2* __restrict__ WML,
             float* __restrict__ O)
{
    const int idx = (int)blockIdx.x * 256 + (int)threadIdx.x;  // NROWS*32 threads
    const int r  = idx >> 5;
    const int dq = idx & 31;
    float2 ml[NSPLIT];
    float M = -1e30f;
    #pragma unroll
    for (int s = 0; s < NSPLIT; ++s) { ml[s] = WML[s * NROWS + r]; M = fmaxf(M, ml[s].x); }
    float e[NSPLIT];
    float den = 0.f;
    #pragma unroll
    for (int s = 0; s < NSPLIT; ++s) { e[s] = exp2f(ml[s].x - M); den += ml[s].y * e[s]; }
    const float inv = 1.0f / den;
    f32x4 o = (f32x4){0.f, 0.f, 0.f, 0.f};
    #pragma unroll
    for (int s = 0; s < NSPLIT; ++s) {
        const f32x4 a = *reinterpret_cast<const f32x4*>(WA + ((size_t)s * NROWS + r) * HD + 4 * dq);
        o += a * e[s];
    }
    o *= inv;
    *reinterpret_cast<f32x4*>(O + (size_t)r * HD + 4 * dq) = o;
}

extern "C" void kernel_launch(void* const* d_in, const int* in_sizes, int n_in,
                              void* d_out, int out_size, void* d_ws, size_t ws_size,
                              hipStream_t stream) {
    const float* q  = (const float*)d_in[0];
    const float* k  = (const float*)d_in[1];
    const float* v  = (const float*)d_in[2];
    const float* kc = (const float*)d_in[3];
    const float* vc = (const float*)d_in[4];
    const int*   pt = (const int*)d_in[5];
    const int*   cx = (const int*)d_in[6];
    float* out = (float*)d_out;

    const size_t waN = (size_t)NROWS * HD * sizeof(float);
    const size_t mlN = (size_t)NROWS * sizeof(float2);

    if (ws_size >= 2 * (waN + mlN)) {
        float*  wa  = (float*)d_ws;
        float2* wml = (float2*)((char*)d_ws + 2 * waN);
        attn_fwd<2><<<dim3(512), dim3(256), 0, stream>>>(q, k, v, kc, vc, pt, cx, wa, wml);
        combine<2><<<dim3(NROWS * 32 / 256), dim3(256), 0, stream>>>(wa, wml, out);
    } else {
        float*  wa  = (float*)d_ws;
        float2* wml = (float2*)((char*)d_ws + waN);
        attn_fwd<1><<<dim3(256), dim3(256), 0, stream>>>(q, k, v, kc, vc, pt, cx, wa, wml);
        combine<1><<<dim3(NROWS * 32 / 256), dim3(256), 0, stream>>>(wa, wml, out);
    }
}